// Round 5
// baseline (415.213 us; speedup 1.0000x reference)
//
#include <hip/hip_runtime.h>
#include <hip/hip_fp16.h>

typedef int v4i __attribute__((ext_vector_type(4)));

#define AS1C(p) ((const __attribute__((address_space(1))) void*)(p))
#define AS3(p)  ((__attribute__((address_space(3))) void*)(p))
#define BARRIER() do { __builtin_amdgcn_s_barrier(); asm volatile("" ::: "memory"); } while (0)

// ---------------------------------------------------------------------------
// int8 GEMM, C = A[M,K]*B[N,K]^T. BN=256, BM in {128,64}. 4 waves (2M x 2N),
// wave tile (BM/2) x 128. mfma_i32_16x16x64_i8, BK=64B.
// 3-buffer LDS ring, depth-2 prefetch, ONE barrier + ONE counted vmcnt per
// K-tile (never 0 mid-loop). 16B-slot XOR swizzle (0 conflicts, r2-verified).
// Column-major-chunked bijective XCD swizzle: resident blocks per XCD share
// B-panels -> staging hits XCD L2.
// EPI 0: fc1 (dequant+bias -> fp16 -> GELU -> gout fp16 + atomicMax amax)
// EPI 1: fc2 (dequant with fp16(amax/127)+bias -> fp16-rounded f32 out)
// ---------------------------------------------------------------------------
template <int EPI, int BM>
__launch_bounds__(256, 2)
__global__ void gemm_p2(const signed char* __restrict__ A, const signed char* __restrict__ Bw,
                        int M, int N, int K,
                        const float* __restrict__ scale_tok, const float* __restrict__ wsc,
                        const float* __restrict__ bias,
                        __half* __restrict__ gout, unsigned int* __restrict__ amax,
                        float* __restrict__ fout) {
  constexpr int ACH = BM / 16;          // A chunks of 1KB (16 rows x 64B)
  constexpr int CT  = ACH + 16;         // + B chunks (256 rows)
  constexpr int CPW = CT / 4;           // loads per wave per K-tile (6 / 5)
  constexpr int MI  = BM / 32;          // A frags per wave (4 / 2)
  constexpr int TB  = CT * 1024;        // bytes per ring buffer (24K / 20K)
  __shared__ __align__(16) char smem[3 * TB];

  const int tid = threadIdx.x;
  const int lane = tid & 63, wave = tid >> 6;
  const int wavem = wave >> 1, waven = wave & 1;

  // column-major-chunked bijective XCD swizzle
  const int gy = gridDim.y;
  int lid;
  {
    const int o = blockIdx.y * gridDim.x + blockIdx.x;
    const int nwg = gridDim.x * gy;
    const int q = nwg >> 3, r = nwg & 7;
    const int x = o & 7, p = o >> 3;
    lid = (x < r ? x * (q + 1) : r * (q + 1) + (x - r) * q) + p;
  }
  const long long t0 = (long long)(lid % gy) * BM;
  const long long n0 = (long long)(lid / gy) * 256;
  const int nk = K >> 6;

  // ---- staging pointers: CPW chunks per wave, 16B/lane, global-side XOR
  const signed char* sp[CPW];
  int dst[CPW];
#pragma unroll
  for (int i = 0; i < CPW; ++i) {
    const int c = wave * CPW + i;
    const bool isA = c < ACH;
    const int lr = (isA ? c : c - ACH) * 16 + (lane >> 2);
    const int gslot = (((lane & 3) ^ ((lr >> 1) & 3)) << 4);
    long long gr = isA ? (t0 + lr) : (n0 + lr);
    const long long rmax = (isA ? (long long)M : (long long)N) - 1;
    if (gr > rmax) gr = rmax;
    sp[i] = (isA ? A : Bw) + gr * (long long)K + gslot;
    dst[i] = c * 1024;
  }

#define STAGE(bi) do { \
    _Pragma("unroll") \
    for (int i = 0; i < CPW; ++i) { \
      __builtin_amdgcn_global_load_lds(AS1C(sp[i]), AS3(&smem[(bi) * TB + dst[i]]), 16, 0, 0); \
      sp[i] += 64; \
    } \
  } while (0)

  // ---- reader offsets (same XOR involution as r2; measured 0 conflicts)
  const int lh = lane & 15;
  const int xs = (((lane >> 4) ^ ((lh >> 1) & 3)) << 4);
  const int offA = wavem * (BM / 2) * 64 + lh * 64 + xs;     // + mi*1024
  const int offB = ACH * 1024 + waven * 8192 + lh * 64 + xs; // + ni*1024

  v4i acc[MI][8] = {};
  v4i a_[MI], b_[8];

  // ---- prologue: stage tiles 0,1; wait tile 0; barrier
  STAGE(0);
  if (nk > 1) {
    STAGE(1);
    if constexpr (CPW == 6) asm volatile("s_waitcnt vmcnt(6)" ::: "memory");
    else                    asm volatile("s_waitcnt vmcnt(5)" ::: "memory");
  } else {
    asm volatile("s_waitcnt vmcnt(0)" ::: "memory");
  }
  BARRIER();

  int cur = 0;
  for (int t = 0; t < nk; ++t) {
    const char* base = &smem[cur * TB];
    int b2 = cur + 2; if (b2 >= 3) b2 -= 3;
    const bool pf = (t + 2) < nk;

    if (pf) STAGE(b2);
#pragma unroll
    for (int mi = 0; mi < MI; ++mi) a_[mi] = *(const v4i*)(base + offA + mi * 1024);
#pragma unroll
    for (int ni = 0; ni < 8; ++ni) b_[ni] = *(const v4i*)(base + offB + ni * 1024);
#pragma unroll
    for (int mi = 0; mi < MI; ++mi)
#pragma unroll
      for (int ni = 0; ni < 8; ++ni)
        acc[mi][ni] = __builtin_amdgcn_mfma_i32_16x16x64_i8(a_[mi], b_[ni], acc[mi][ni], 0, 0, 0);

    asm volatile("s_waitcnt lgkmcnt(0)" ::: "memory");
    if (pf) {
      if constexpr (CPW == 6) asm volatile("s_waitcnt vmcnt(6)" ::: "memory");
      else                    asm volatile("s_waitcnt vmcnt(5)" ::: "memory");
    } else {
      asm volatile("s_waitcnt vmcnt(0)" ::: "memory");
    }
    BARRIER();
    cur += 1; if (cur >= 3) cur = 0;
  }
#undef STAGE

  // ---- epilogue
  long long cidx[8]; float w8[8], bi8[8]; bool cok[8];
#pragma unroll
  for (int ni = 0; ni < 8; ++ni) {
    cidx[ni] = n0 + waven * 128 + ni * 16 + lh;
    cok[ni] = cidx[ni] < N;
    w8[ni] = cok[ni] ? wsc[cidx[ni]] : 0.f;
    bi8[ni] = cok[ni] ? bias[cidx[ni]] : 0.f;
  }
  if (EPI == 0) {
#pragma unroll
    for (int mi = 0; mi < MI; ++mi) {
#pragma unroll
      for (int j = 0; j < 4; ++j) {
        const long long t = t0 + wavem * (BM / 2) + mi * 16 + (lane >> 4) * 4 + j;
        const bool valid = t < M;
        const float st = valid ? scale_tok[t] : 0.f;
        float rowmax = 0.f;
#pragma unroll
        for (int ni = 0; ni < 8; ++ni) {
          float v = (float)acc[mi][ni][j] * st * w8[ni] + bi8[ni];
          v = __half2float(__float2half(v));  // fc1 rounds to fp16 (reference)
          const float gl = 0.5f * v * (1.f + erff(v * 0.70710678118654752f));
          rowmax = fmaxf(rowmax, fabsf(gl));
          if (valid && cok[ni]) gout[t * (long long)N + cidx[ni]] = __float2half(gl);
        }
#pragma unroll
        for (int m = 1; m < 16; m <<= 1) rowmax = fmaxf(rowmax, __shfl_xor(rowmax, m));
        if (valid && lh == 0) atomicMax(&amax[t], __float_as_uint(rowmax));
      }
    }
  } else {
#pragma unroll
    for (int mi = 0; mi < MI; ++mi) {
#pragma unroll
      for (int j = 0; j < 4; ++j) {
        const long long t = t0 + wavem * (BM / 2) + mi * 16 + (lane >> 4) * 4 + j;
        if (t < M) {
          const float am = __uint_as_float(amax[t]);
          const float st = __half2float(__float2half(am * (1.f / 127.f)));
#pragma unroll
          for (int ni = 0; ni < 8; ++ni) {
            const float v = (float)acc[mi][ni][j] * st * w8[ni] + bi8[ni];
            if (cok[ni]) fout[t * (long long)N + cidx[ni]] = __half2float(__float2half(v));
          }
        }
      }
    }
  }
}

// ---------------------------------------------------------------------------
// int32 -> int8 packing for x, w1, w2 (+ zero the amax buffer each call)
// ---------------------------------------------------------------------------
__global__ void pack_all(const int* __restrict__ a, const int* __restrict__ b,
                         const int* __restrict__ c,
                         signed char* __restrict__ pa, signed char* __restrict__ pb,
                         signed char* __restrict__ pc,
                         unsigned int* __restrict__ amax,
                         long long na, long long nb, long long nc, int T) {
  const long long gid = blockIdx.x * (long long)blockDim.x + threadIdx.x;
  if (gid < T) amax[gid] = 0u;
  const long long n4a = na >> 2, n4b = nb >> 2, n4c = nc >> 2;
  const long long tot = n4a + n4b + n4c;
  const long long stride = (long long)gridDim.x * blockDim.x;
  for (long long u = gid; u < tot; u += stride) {
    const int* src; signed char* dst; long long loc;
    if (u < n4a)            { src = a; dst = pa; loc = u; }
    else if (u < n4a + n4b) { src = b; dst = pb; loc = u - n4a; }
    else                    { src = c; dst = pc; loc = u - n4a - n4b; }
    const int4 v = *(const int4*)(src + (loc << 2));
    const unsigned out = (unsigned)(v.x & 0xff) | ((unsigned)(v.y & 0xff) << 8) |
                         ((unsigned)(v.z & 0xff) << 16) | ((unsigned)(v.w & 0xff) << 24);
    *(unsigned*)(dst + (loc << 2)) = out;
  }
}

// ---------------------------------------------------------------------------
// per-token dynamic int8 quantization of the GELU output
// ---------------------------------------------------------------------------
__global__ void gelu_quant(const __half* __restrict__ g, const unsigned int* __restrict__ amax,
                           signed char* __restrict__ q, long long total, int I) {
  const long long nchunk = total >> 3;
  const long long stride = (long long)gridDim.x * blockDim.x;
  for (long long c = blockIdx.x * (long long)blockDim.x + threadIdx.x; c < nchunk; c += stride) {
    const long long base = c << 3;  // 8 elems, never crosses a row (I % 8 == 0)
    const int t = (int)(base / I);
    const float am = __uint_as_float(amax[t]);
    const float s = fmaxf(__half2float(__float2half(am * (1.f / 127.f))), 1e-8f);
    const float inv = 1.f / s;
    const int4 raw = *(const int4*)(g + base);
    const __half2* h2 = (const __half2*)&raw;
    union { signed char b[8]; int2 v; } u;
#pragma unroll
    for (int k = 0; k < 4; ++k) {
      const float2 f = __half22float2(h2[k]);
      const float q0 = fminf(fmaxf(rintf(f.x * inv), -128.f), 127.f);
      const float q1 = fminf(fmaxf(rintf(f.y * inv), -128.f), 127.f);
      u.b[k * 2]     = (signed char)(int)q0;
      u.b[k * 2 + 1] = (signed char)(int)q1;
    }
    *(int2*)(q + base) = u.v;
  }
}

extern "C" void kernel_launch(void* const* d_in, const int* in_sizes, int n_in,
                              void* d_out, int out_size, void* d_ws, size_t ws_size,
                              hipStream_t stream) {
  const int* hs = (const int*)d_in[0];
  const float* scale_in = (const float*)d_in[1];   // fp16 in reference -> f32 buffer
  const int* w1 = (const int*)d_in[2];
  const float* w1s = (const float*)d_in[3];
  const float* b1 = (const float*)d_in[4];
  const int* w2 = (const int*)d_in[5];
  const float* w2s = (const float*)d_in[6];
  const float* b2 = (const float*)d_in[7];

  const int T = in_sizes[1];        // 2050
  const int I = in_sizes[3];        // 12800
  const int H = in_sizes[6];        // 3200

  char* ws = (char*)d_ws;
  unsigned int* amax = (unsigned int*)ws;                    // T u32 (16KB pad)
  signed char* px  = (signed char*)(ws + 16384);             // T*H
  signed char* pw1 = px + (size_t)T * H;                     // I*H
  signed char* pw2 = pw1 + (size_t)I * H;                    // H*I
  __half* gbuf = (__half*)(pw2 + (size_t)H * I);             // T*I fp16
  signed char* qbuf = (signed char*)(gbuf + (size_t)T * I);  // T*I

  const long long nx = (long long)T * H, nw1 = (long long)I * H, nw2 = (long long)H * I;

  pack_all<<<2048, 256, 0, stream>>>(hs, w1, w2, px, pw1, pw2, amax, nx, nw1, nw2, T);

  // fc1: 128x256 tiles, grid 50 x 17 = 850 blocks, 2/CU
  dim3 g1(I / 256, (T + 127) / 128);
  gemm_p2<0, 128><<<g1, 256, 0, stream>>>(px, pw1, T, I, H, scale_in, w1s, b1, gbuf, amax, nullptr);

  gelu_quant<<<2048, 256, 0, stream>>>(gbuf, amax, qbuf, (long long)T * I, I);

  // fc2: 64x256 tiles, grid 13 x 33 = 429 blocks
  dim3 g2((H + 255) / 256, (T + 63) / 64);
  gemm_p2<1, 64><<<g2, 256, 0, stream>>>(qbuf, pw2, T, H, I, nullptr, w2s, b2, nullptr, amax, (float*)d_out);
}

// Round 6
// 374.463 us; speedup vs baseline: 1.1088x; 1.1088x over previous
//
#include <hip/hip_runtime.h>
#include <hip/hip_fp16.h>

typedef int v4i __attribute__((ext_vector_type(4)));

#define AS1C(p) ((const __attribute__((address_space(1))) void*)(p))
#define AS3(p)  ((__attribute__((address_space(3))) void*)(p))
#define BARRIER() do { __builtin_amdgcn_s_barrier(); asm volatile("" ::: "memory"); } while (0)

// ---------------------------------------------------------------------------
// Fat-phase int8 GEMM, C = A[M,K]*B[N,K]^T. BN=256, BM in {256,128}.
// 8 waves (2M x 4N), wave tile (BM/2) x 64... cols: 4 n-frags of 16.
// mfma_i32_16x16x64_i8, BK=64B per K-step.
// Ring of 4 LDS buffers, prefetch distance 3, ONE fence (counted vmcnt +
// barrier) per K-step, two setprio-wrapped MFMA clusters (MI/2 x 4 each).
// 16B-slot XOR swizzle (0 conflicts, verified r2-r5).
// EPI 0: fc1 (dequant+bias -> fp16 -> GELU -> gout fp16 + atomicMax amax)
// EPI 1: fc2 (dequant with fp16(amax/127)+bias -> fp16-rounded f32 out)
// ---------------------------------------------------------------------------
template <int EPI, int BM>
__launch_bounds__(512, 1)
__global__ void gemm_fat(const signed char* __restrict__ A, const signed char* __restrict__ Bw,
                         int M, int N, int K,
                         const float* __restrict__ scale_tok, const float* __restrict__ wsc,
                         const float* __restrict__ bias,
                         __half* __restrict__ gout, unsigned int* __restrict__ amax,
                         float* __restrict__ fout) {
  constexpr int ACH = BM / 16;          // A chunks (1KB = 16 rows x 64B)
  constexpr int CT  = ACH + 16;         // + B chunks (256 rows)
  constexpr int CPW = CT / 8;           // loads per thread per K-step (4 / 3)
  constexpr int TB  = CT * 1024;        // ring buffer bytes (32K / 24K)
  constexpr int MI  = BM / 32;          // A frags per wave (8 / 4)
  constexpr int MH  = MI / 2;           // frags per MFMA cluster
  __shared__ __align__(16) char smem[4 * TB];

  const int tid = threadIdx.x;
  const int lane = tid & 63, wave = tid >> 6;
  const int wavem = wave >> 2, waven = wave & 3;

  // chunked bijective XCD swizzle: consecutive lid share the B-panel (n0)
  const int gy = gridDim.y;
  int lid;
  {
    const int o = blockIdx.y * gridDim.x + blockIdx.x;
    const int nwg = gridDim.x * gy;
    const int q = nwg >> 3, r = nwg & 7;
    const int x = o & 7, p = o >> 3;
    lid = (x < r ? x * (q + 1) : r * (q + 1) + (x - r) * q) + p;
  }
  const long long t0 = (long long)(lid % gy) * BM;
  const long long n0 = (long long)(lid / gy) * 256;
  const int nk = K >> 6;

  // ---- staging pointers: CPW 1KB-chunks per wave, 16B/lane, global-side XOR
  const signed char* sp[CPW];
  int dst[CPW];
#pragma unroll
  for (int i = 0; i < CPW; ++i) {
    const int c = wave * CPW + i;
    const bool isA = c < ACH;
    const int lr = (isA ? c : c - ACH) * 16 + (lane >> 2);
    const int gslot = (((lane & 3) ^ ((lr >> 1) & 3)) << 4);
    long long gr = isA ? (t0 + lr) : (n0 + lr);
    const long long rmax = (isA ? (long long)M : (long long)N) - 1;
    if (gr > rmax) gr = rmax;
    sp[i] = (isA ? A : Bw) + gr * (long long)K + gslot;
    dst[i] = c * 1024;
  }

#define STAGE(bi) do { \
    _Pragma("unroll") \
    for (int i = 0; i < CPW; ++i) { \
      __builtin_amdgcn_global_load_lds(AS1C(sp[i]), AS3(&smem[(bi) * TB + dst[i]]), 16, 0, 0); \
      sp[i] += 64; \
    } \
  } while (0)

  // ---- reader offsets (XOR involution; 0 conflicts measured)
  const int lh = lane & 15;
  const int xs = (((lane >> 4) ^ ((lh >> 1) & 3)) << 4);
  const int offA = wavem * (BM / 2) * 64 + lh * 64 + xs;     // + mi*1024
  const int offB = ACH * 1024 + waven * 4096 + lh * 64 + xs; // + ni*1024

  v4i acc[MI][4] = {};

  // ---- prologue: stage tiles 0,1,2 (ring slots 0,1,2)
  STAGE(0);
  if (nk > 1) STAGE(1);
  if (nk > 2) STAGE(2);

  int cur = 0;
  for (int t = 0; t < nk; ++t) {
    // fence: tile t complete everywhere (counted; never drains mid-loop)
    if (t < nk - 2) {
      if constexpr (CPW == 4) asm volatile("s_waitcnt vmcnt(8)" ::: "memory");
      else                    asm volatile("s_waitcnt vmcnt(6)" ::: "memory");
    } else if (t == nk - 2) {
      if constexpr (CPW == 4) asm volatile("s_waitcnt vmcnt(4)" ::: "memory");
      else                    asm volatile("s_waitcnt vmcnt(3)" ::: "memory");
    } else {
      asm volatile("s_waitcnt vmcnt(0)" ::: "memory");
    }
    BARRIER();

    const char* base = &smem[cur * TB];
    if (t + 3 < nk) STAGE((cur + 3) & 3);   // slot freed by the barrier above

    v4i b_[4], a0_[MH], a1_[MH];
#pragma unroll
    for (int mi = 0; mi < MH; ++mi) a0_[mi] = *(const v4i*)(base + offA + mi * 1024);
#pragma unroll
    for (int ni = 0; ni < 4; ++ni) b_[ni] = *(const v4i*)(base + offB + ni * 1024);

    __builtin_amdgcn_s_setprio(1);
#pragma unroll
    for (int mi = 0; mi < MH; ++mi)
#pragma unroll
      for (int ni = 0; ni < 4; ++ni)
        acc[mi][ni] = __builtin_amdgcn_mfma_i32_16x16x64_i8(a0_[mi], b_[ni], acc[mi][ni], 0, 0, 0);
    __builtin_amdgcn_s_setprio(0);

#pragma unroll
    for (int mi = 0; mi < MH; ++mi) a1_[mi] = *(const v4i*)(base + offA + (MH + mi) * 1024);

    __builtin_amdgcn_s_setprio(1);
#pragma unroll
    for (int mi = 0; mi < MH; ++mi)
#pragma unroll
      for (int ni = 0; ni < 4; ++ni)
        acc[MH + mi][ni] = __builtin_amdgcn_mfma_i32_16x16x64_i8(a1_[mi], b_[ni], acc[MH + mi][ni], 0, 0, 0);
    __builtin_amdgcn_s_setprio(0);

    cur = (cur + 1) & 3;
  }
#undef STAGE

  // ---- epilogue
  long long cidx[4]; float w4[4], bi4[4]; bool cok[4];
#pragma unroll
  for (int ni = 0; ni < 4; ++ni) {
    cidx[ni] = n0 + waven * 64 + ni * 16 + lh;
    cok[ni] = cidx[ni] < N;
    w4[ni] = cok[ni] ? wsc[cidx[ni]] : 0.f;
    bi4[ni] = cok[ni] ? bias[cidx[ni]] : 0.f;
  }
  if (EPI == 0) {
#pragma unroll
    for (int mi = 0; mi < MI; ++mi) {
#pragma unroll
      for (int j = 0; j < 4; ++j) {
        const long long t = t0 + wavem * (BM / 2) + mi * 16 + (lane >> 4) * 4 + j;
        const bool valid = t < M;
        const float st = valid ? scale_tok[t] : 0.f;
        float rowmax = 0.f;
#pragma unroll
        for (int ni = 0; ni < 4; ++ni) {
          float v = (float)acc[mi][ni][j] * st * w4[ni] + bi4[ni];
          v = __half2float(__float2half(v));  // fc1 rounds to fp16 (reference)
          const float gl = 0.5f * v * (1.f + erff(v * 0.70710678118654752f));
          rowmax = fmaxf(rowmax, fabsf(gl));
          if (valid && cok[ni]) gout[t * (long long)N + cidx[ni]] = __float2half(gl);
        }
#pragma unroll
        for (int m = 1; m < 16; m <<= 1) rowmax = fmaxf(rowmax, __shfl_xor(rowmax, m));
        if (valid && lh == 0) atomicMax(&amax[t], __float_as_uint(rowmax));
      }
    }
  } else {
#pragma unroll
    for (int mi = 0; mi < MI; ++mi) {
#pragma unroll
      for (int j = 0; j < 4; ++j) {
        const long long t = t0 + wavem * (BM / 2) + mi * 16 + (lane >> 4) * 4 + j;
        if (t < M) {
          const float am = __uint_as_float(amax[t]);
          const float st = __half2float(__float2half(am * (1.f / 127.f)));
#pragma unroll
          for (int ni = 0; ni < 4; ++ni) {
            const float v = (float)acc[mi][ni][j] * st * w4[ni] + bi4[ni];
            if (cok[ni]) fout[t * (long long)N + cidx[ni]] = __half2float(__float2half(v));
          }
        }
      }
    }
  }
}

// ---------------------------------------------------------------------------
// int32 -> int8 packing for x, w1, w2 (+ zero the amax buffer each call)
// ---------------------------------------------------------------------------
__global__ void pack_all(const int* __restrict__ a, const int* __restrict__ b,
                         const int* __restrict__ c,
                         signed char* __restrict__ pa, signed char* __restrict__ pb,
                         signed char* __restrict__ pc,
                         unsigned int* __restrict__ amax,
                         long long na, long long nb, long long nc, int T) {
  const long long gid = blockIdx.x * (long long)blockDim.x + threadIdx.x;
  if (gid < T) amax[gid] = 0u;
  const long long n4a = na >> 2, n4b = nb >> 2, n4c = nc >> 2;
  const long long tot = n4a + n4b + n4c;
  const long long stride = (long long)gridDim.x * blockDim.x;
  for (long long u = gid; u < tot; u += stride) {
    const int* src; signed char* dst; long long loc;
    if (u < n4a)            { src = a; dst = pa; loc = u; }
    else if (u < n4a + n4b) { src = b; dst = pb; loc = u - n4a; }
    else                    { src = c; dst = pc; loc = u - n4a - n4b; }
    const int4 v = *(const int4*)(src + (loc << 2));
    const unsigned out = (unsigned)(v.x & 0xff) | ((unsigned)(v.y & 0xff) << 8) |
                         ((unsigned)(v.z & 0xff) << 16) | ((unsigned)(v.w & 0xff) << 24);
    *(unsigned*)(dst + (loc << 2)) = out;
  }
}

// ---------------------------------------------------------------------------
// per-token dynamic int8 quantization of the GELU output
// ---------------------------------------------------------------------------
__global__ void gelu_quant(const __half* __restrict__ g, const unsigned int* __restrict__ amax,
                           signed char* __restrict__ q, long long total, int I) {
  const long long nchunk = total >> 3;
  const long long stride = (long long)gridDim.x * blockDim.x;
  for (long long c = blockIdx.x * (long long)blockDim.x + threadIdx.x; c < nchunk; c += stride) {
    const long long base = c << 3;  // 8 elems, never crosses a row (I % 8 == 0)
    const int t = (int)(base / I);
    const float am = __uint_as_float(amax[t]);
    const float s = fmaxf(__half2float(__float2half(am * (1.f / 127.f))), 1e-8f);
    const float inv = 1.f / s;
    const int4 raw = *(const int4*)(g + base);
    const __half2* h2 = (const __half2*)&raw;
    union { signed char b[8]; int2 v; } u;
#pragma unroll
    for (int k = 0; k < 4; ++k) {
      const float2 f = __half22float2(h2[k]);
      const float q0 = fminf(fmaxf(rintf(f.x * inv), -128.f), 127.f);
      const float q1 = fminf(fmaxf(rintf(f.y * inv), -128.f), 127.f);
      u.b[k * 2]     = (signed char)(int)q0;
      u.b[k * 2 + 1] = (signed char)(int)q1;
    }
    *(int2*)(q + base) = u.v;
  }
}

extern "C" void kernel_launch(void* const* d_in, const int* in_sizes, int n_in,
                              void* d_out, int out_size, void* d_ws, size_t ws_size,
                              hipStream_t stream) {
  const int* hs = (const int*)d_in[0];
  const float* scale_in = (const float*)d_in[1];   // fp16 in reference -> f32 buffer
  const int* w1 = (const int*)d_in[2];
  const float* w1s = (const float*)d_in[3];
  const float* b1 = (const float*)d_in[4];
  const int* w2 = (const int*)d_in[5];
  const float* w2s = (const float*)d_in[6];
  const float* b2 = (const float*)d_in[7];

  const int T = in_sizes[1];        // 2050
  const int I = in_sizes[3];        // 12800
  const int H = in_sizes[6];        // 3200

  char* ws = (char*)d_ws;
  unsigned int* amax = (unsigned int*)ws;                    // T u32 (16KB pad)
  signed char* px  = (signed char*)(ws + 16384);             // T*H
  signed char* pw1 = px + (size_t)T * H;                     // I*H
  signed char* pw2 = pw1 + (size_t)I * H;                    // H*I
  __half* gbuf = (__half*)(pw2 + (size_t)H * I);             // T*I fp16
  signed char* qbuf = (signed char*)(gbuf + (size_t)T * I);  // T*I

  const long long nx = (long long)T * H, nw1 = (long long)I * H, nw2 = (long long)H * I;

  pack_all<<<2048, 256, 0, stream>>>(hs, w1, w2, px, pw1, pw2, amax, nx, nw1, nw2, T);

  // fc1: 256x256 tiles, grid 50 x 9 = 450 blocks
  dim3 g1(I / 256, (T + 255) / 256);
  gemm_fat<0, 256><<<g1, 512, 0, stream>>>(px, pw1, T, I, H, scale_in, w1s, b1, gbuf, amax, nullptr);

  gelu_quant<<<2048, 256, 0, stream>>>(gbuf, amax, qbuf, (long long)T * I, I);

  // fc2: 128x256 tiles, grid 13 x 17 = 221 blocks
  dim3 g2((H + 255) / 256, (T + 127) / 128);
  gemm_fat<1, 128><<<g2, 512, 0, stream>>>(qbuf, pw2, T, H, I, nullptr, w2s, b2, nullptr, amax, (float*)d_out);
}